// Round 3
// baseline (867.655 us; speedup 1.0000x reference)
//
#include <hip/hip_runtime.h>

// ---------------------------------------------------------------------------
// NASNet controller: 8 sequential LSTM steps (B=4096, H=512) + 16 decisions.
//  - Steps 1-4 run on class representatives (1/8/64/512 rows): rows only
//    differ through sampled op tokens (8^s classes).
//  - Steps 5-7: full GEMMs on the MFMA pipe via split-bf16 (hi+lo) emulation:
//    A*B ~= Ahi*Bhi + Ahi*Blo + Alo*Bhi  == one bf16 GEMM with K=1536.
//    A phys = [hi|lo] (K=1024) with source-address remap for the dup block.
//    W_cat rows are gate-interleaved (ct = 4j+gate) so the epilogue fuses the
//    LSTM pointwise per (row,j) after an LDS round-trip of the C tile.
// ---------------------------------------------------------------------------

constexpr int Bsz = 4096;
constexpr int Hsz = 512;
constexpr int G4H = 2048;

typedef unsigned short ushort_t;
using short8 = __attribute__((ext_vector_type(8))) short;
using f32x4 = __attribute__((ext_vector_type(4))) float;

__device__ __forceinline__ ushort_t f2bf_hi(float f) {
  unsigned u = __float_as_uint(f);
  u += 0x7FFF + ((u >> 16) & 1);  // RNE
  return (ushort_t)(u >> 16);
}
__device__ __forceinline__ float bf2f(ushort_t h) {
  return __uint_as_float((unsigned)h << 16);
}

__device__ __forceinline__ void glds16(const void* gsrc, void* ldst) {
  __builtin_amdgcn_global_load_lds(
      (const __attribute__((address_space(1))) void*)gsrc,
      (__attribute__((address_space(3))) void*)ldst, 16, 0, 0);
}

// ---------------- E = emb @ w_ih^T + b_ih + b_hh (std + ct-permuted) -------
__global__ __launch_bounds__(256) void precompute_E(
    const float* __restrict__ emb, const float* __restrict__ w_ih,
    const float* __restrict__ b_ih, const float* __restrict__ b_hh,
    float* __restrict__ E, float* __restrict__ Eperm) {
  int idx = blockIdx.x * 256 + threadIdx.x;  // t*2048 + col
  int t = idx >> 11;
  int col = idx & 2047;
  const float* er = emb + (size_t)t * Hsz;
  const float* wr = w_ih + (size_t)col * Hsz;
  float acc = 0.0f;
  for (int k = 0; k < Hsz; k += 4) {
    float4 e = *(const float4*)(er + k);
    float4 w = *(const float4*)(wr + k);
    acc += e.x * w.x + e.y * w.y + e.z * w.z + e.w * w.w;
  }
  float v = acc + b_ih[col] + b_hh[col];
  E[idx] = v;
  int g = col >> 9, j = col & 511;
  Eperm[(size_t)t * G4H + (j << 2) + g] = v;
}

// ---------------- W_cat: [2048 ct rows][1536] bf16 = [hi | lo | hi] --------
__global__ __launch_bounds__(256) void build_wcat(
    const float* __restrict__ w_hh, ushort_t* __restrict__ Wcat) {
  int ct = blockIdx.y;
  int k = blockIdx.x * 256 + threadIdx.x;  // 0..1535
  int j = ct >> 2, g = ct & 3;
  const float* srcrow = w_hh + (size_t)(g * 512 + j) * Hsz;
  ushort_t out;
  if (k < 512) {
    out = f2bf_hi(srcrow[k]);
  } else if (k < 1024) {
    float x = srcrow[k - 512];
    ushort_t hi = f2bf_hi(x);
    out = f2bf_hi(x - bf2f(hi));
  } else {
    out = f2bf_hi(srcrow[k - 1024]);
  }
  Wcat[(size_t)ct * 1536 + k] = out;
}

// ---------------- class GEMM: G[q][col] = dot(h[q], w[col]) ----------------
__global__ __launch_bounds__(256) void class_gemm(
    const float* __restrict__ h, const float* __restrict__ w,
    float* __restrict__ G, int nq) {
  const int wid = (blockIdx.x << 2) + (threadIdx.x >> 6);
  const int lane = threadIdx.x & 63;
  const int q = wid >> 11;
  const int col = wid & 2047;
  if (q >= nq) return;
  const float* hr = h + (size_t)q * Hsz + (lane << 3);
  const float* wr = w + (size_t)col * Hsz + (lane << 3);
  float4 a0 = *(const float4*)(hr);
  float4 a1 = *(const float4*)(hr + 4);
  float4 b0 = *(const float4*)(wr);
  float4 b1 = *(const float4*)(wr + 4);
  float v = a0.x * b0.x + a0.y * b0.y + a0.z * b0.z + a0.w * b0.w +
            a1.x * b1.x + a1.y * b1.y + a1.z * b1.z + a1.w * b1.w;
#pragma unroll
  for (int off = 32; off > 0; off >>= 1) v += __shfl_xor(v, off, 64);
  if (lane == 0) G[(size_t)q * G4H + col] = v;
}

// ---------------- 64x64-tiled fp32 GEMM (step 4, M=512) --------------------
__global__ __launch_bounds__(256) void gemm64(
    const float* __restrict__ A, const float* __restrict__ Bw,
    float* __restrict__ G) {
  constexpr int LDA = 68;
  __shared__ float As[16 * LDA];
  __shared__ float Bs[16 * LDA];
  const int tid = threadIdx.x;
  const int bx = blockIdx.x & 31;
  const int by = blockIdx.x >> 5;
  const int r0 = by * 64, c0 = bx * 64;
  const int tx = tid & 15, ty = tid >> 4;
  const int lr = tid >> 2;
  const int lk = (tid & 3) << 2;
  const float* Ar = A + (size_t)(r0 + lr) * Hsz;
  const float* Br = Bw + (size_t)(c0 + lr) * Hsz;
  float acc[4][4];
#pragma unroll
  for (int i = 0; i < 4; ++i)
#pragma unroll
    for (int j = 0; j < 4; ++j) acc[i][j] = 0.0f;

  for (int k0 = 0; k0 < Hsz; k0 += 16) {
    float4 a = *(const float4*)(Ar + k0 + lk);
    float4 b = *(const float4*)(Br + k0 + lk);
    __syncthreads();
    As[(lk + 0) * LDA + lr] = a.x;
    As[(lk + 1) * LDA + lr] = a.y;
    As[(lk + 2) * LDA + lr] = a.z;
    As[(lk + 3) * LDA + lr] = a.w;
    Bs[(lk + 0) * LDA + lr] = b.x;
    Bs[(lk + 1) * LDA + lr] = b.y;
    Bs[(lk + 2) * LDA + lr] = b.z;
    Bs[(lk + 3) * LDA + lr] = b.w;
    __syncthreads();
#pragma unroll
    for (int kk = 0; kk < 16; ++kk) {
      float4 av = *(const float4*)&As[kk * LDA + (ty << 2)];
      float4 bv = *(const float4*)&Bs[kk * LDA + (tx << 2)];
      float avs[4] = {av.x, av.y, av.z, av.w};
      float bvs[4] = {bv.x, bv.y, bv.z, bv.w};
#pragma unroll
      for (int i = 0; i < 4; ++i)
#pragma unroll
        for (int j = 0; j < 4; ++j) acc[i][j] = fmaf(avs[i], bvs[j], acc[i][j]);
    }
  }
#pragma unroll
  for (int i = 0; i < 4; ++i)
#pragma unroll
    for (int j = 0; j < 4; ++j)
      G[(size_t)(r0 + (ty << 2) + i) * G4H + c0 + (tx << 2) + j] = acc[i][j];
}

// ---------------- class pointwise ------------------------------------------
__global__ __launch_bounds__(256) void step_pw(
    const float* __restrict__ G, const float* __restrict__ E,
    const float* __restrict__ c_prev, float* __restrict__ h_out,
    float* __restrict__ c_out, int nq) {
  int idx = blockIdx.x * 256 + threadIdx.x;
  if (idx >= nq * Hsz) return;
  int q = idx >> 9, j = idx & 511;
  int gq = q >> 3, er = q & 7;
  const float* Eg = E + (size_t)er * G4H;
  float iv = Eg[j], fv = Eg[512 + j], gv = Eg[1024 + j], ov = Eg[1536 + j];
  if (G) {
    const float* Gg = G + (size_t)gq * G4H;
    iv += Gg[j]; fv += Gg[512 + j]; gv += Gg[1024 + j]; ov += Gg[1536 + j];
  }
  float cp = c_prev ? c_prev[(size_t)gq * Hsz + j] : 0.0f;
  float ig = 1.0f / (1.0f + expf(-iv));
  float fg = 1.0f / (1.0f + expf(-fv));
  float gg = tanhf(gv);
  float og = 1.0f / (1.0f + expf(-ov));
  float cn = fg * cp + ig * gg;
  c_out[idx] = cn;
  h_out[idx] = og * tanhf(cn);
}

// ---------------- step-4 expansion: classes (512) -> rows (4096) -----------
// also emits the step-5 GEMM input A_cat = [hi | lo] bf16.
__global__ __launch_bounds__(256) void expand_pw(
    const float* __restrict__ G, const float* __restrict__ E,
    const float* __restrict__ c4, const int* __restrict__ cls3,
    const int* __restrict__ act3, float* __restrict__ h_out,
    float* __restrict__ c_out, ushort_t* __restrict__ Acat) {
  int idx = blockIdx.x * 256 + threadIdx.x;
  int r = idx >> 9, j = idx & 511;
  int q = cls3[r], er = act3[r];
  const float* Eg = E + (size_t)er * G4H;
  const float* Gg = G + (size_t)q * G4H;
  float iv = Gg[j] + Eg[j];
  float fv = Gg[512 + j] + Eg[512 + j];
  float gv = Gg[1024 + j] + Eg[1024 + j];
  float ov = Gg[1536 + j] + Eg[1536 + j];
  float cp = c4[(size_t)q * Hsz + j];
  float ig = 1.0f / (1.0f + expf(-iv));
  float fg = 1.0f / (1.0f + expf(-fv));
  float gg = tanhf(gv);
  float og = 1.0f / (1.0f + expf(-ov));
  float cn = fg * cp + ig * gg;
  float hn = og * tanhf(cn);
  c_out[idx] = cn;
  h_out[idx] = hn;
  ushort_t hi = f2bf_hi(hn);
  Acat[(size_t)r * 1024 + j] = hi;
  Acat[(size_t)r * 1024 + 512 + j] = f2bf_hi(hn - bf2f(hi));
}

// ---------------- split-bf16 MFMA GEMM + fused LSTM pointwise --------------
// C[4096 x 2048ct] = Acat(logical [hi|hi|lo]) @ Wcat^T (rows = ct, [hi|lo|hi])
// tile 128x128, BK=64, 4 waves x (4x4 16x16x32 tiles).
__global__ __launch_bounds__(256) void gemm_bf16_lstm(
    const ushort_t* __restrict__ Acat, const ushort_t* __restrict__ Wcat,
    const float* __restrict__ Eperm, const int* __restrict__ act,
    float* __restrict__ cF, float* __restrict__ h_out,
    ushort_t* __restrict__ Aout) {
  __shared__ union {
    struct { ushort_t A[128 * 64]; ushort_t B[128 * 64]; } s;  // 32 KB
    float C[64 * 132];                                         // 33.8 KB
  } sm;

  const int tid = threadIdx.x;
  const int wave = tid >> 6, lane = tid & 63;
  const int bx = blockIdx.x & 15;   // 16 col tiles
  const int by = blockIdx.x >> 4;   // 32 row tiles
  const int r0 = by * 128, c0 = bx * 128;
  const int wr = (wave >> 1) * 64, wc = (wave & 1) * 64;
  const int mrow = lane & 15, quad = lane >> 4;

  f32x4 acc[4][4];
#pragma unroll
  for (int i = 0; i < 4; ++i)
#pragma unroll
    for (int jt = 0; jt < 4; ++jt) acc[i][jt] = (f32x4){0.f, 0.f, 0.f, 0.f};

  for (int k0 = 0; k0 < 1536; k0 += 64) {
    const int ak = (k0 < 512) ? k0 : k0 - 512;  // A dup-block remap
    __syncthreads();  // prior iter's ds_reads done before overwrite
    // 32 regions of 1024 B (16 A + 16 B); wave w stages regions q*4+w.
#pragma unroll
    for (int q = 0; q < 8; ++q) {
      const int g = q * 4 + wave;
      if (g < 16) {
        const int row = r0 + g * 8 + (lane >> 3);
        glds16(Acat + (size_t)row * 1024 + ak + ((lane & 7) << 3),
               (char*)sm.s.A + g * 1024);
      } else {
        const int row = c0 + (g - 16) * 8 + (lane >> 3);
        glds16(Wcat + (size_t)row * 1536 + k0 + ((lane & 7) << 3),
               (char*)sm.s.B + (g - 16) * 1024);
      }
    }
    __syncthreads();
#pragma unroll
    for (int kk = 0; kk < 2; ++kk) {
      short8 a[4], b[4];
#pragma unroll
      for (int i = 0; i < 4; ++i)
        a[i] = *(const short8*)&sm.s.A[(wr + i * 16 + mrow) * 64 + kk * 32 + quad * 8];
#pragma unroll
      for (int jt = 0; jt < 4; ++jt)
        b[jt] = *(const short8*)&sm.s.B[(wc + jt * 16 + mrow) * 64 + kk * 32 + quad * 8];
#pragma unroll
      for (int i = 0; i < 4; ++i)
#pragma unroll
        for (int jt = 0; jt < 4; ++jt)
          acc[i][jt] = __builtin_amdgcn_mfma_f32_16x16x32_bf16(
              a[i], b[jt], acc[i][jt], 0, 0, 0);
    }
  }

  // ---- epilogue: two 64-row phases through LDS, fused LSTM pointwise ----
  const int jj = tid & 31;         // j-local 0..31
  const int rbase = tid >> 5;      // 0..7
#pragma unroll
  for (int p = 0; p < 2; ++p) {
    __syncthreads();  // phase 0: K-loop reads done; phase 1: prev consume done
    if ((wr >> 6) == p) {
#pragma unroll
      for (int i = 0; i < 4; ++i)
#pragma unroll
        for (int jt = 0; jt < 4; ++jt)
#pragma unroll
          for (int rg = 0; rg < 4; ++rg)
            sm.C[(i * 16 + quad * 4 + rg) * 132 + wc + jt * 16 + mrow] =
                acc[i][jt][rg];
    }
    __syncthreads();
#pragma unroll
    for (int rp = 0; rp < 8; ++rp) {
      const int rl = rbase * 8 + rp;           // 0..63
      const int grow = r0 + p * 64 + rl;
      float4 g4 = *(float4*)&sm.C[rl * 132 + jj * 4];
      const int a = act[grow];
      const int jglob = (c0 >> 2) + jj;        // 0..511
      float4 e4 = *(const float4*)&Eperm[(size_t)a * G4H + c0 + jj * 4];
      float iv = g4.x + e4.x, fv = g4.y + e4.y;
      float gv = g4.z + e4.z, ov = g4.w + e4.w;
      float ig = 1.0f / (1.0f + expf(-iv));
      float fg = 1.0f / (1.0f + expf(-fv));
      float gg = tanhf(gv);
      float og = 1.0f / (1.0f + expf(-ov));
      const size_t ci = (size_t)grow * Hsz + jglob;
      float cn = fg * cF[ci] + ig * gg;
      float hn = og * tanhf(cn);
      cF[ci] = cn;
      h_out[ci] = hn;
      ushort_t hi = f2bf_hi(hn);
      Aout[(size_t)grow * 1024 + jglob] = hi;
      Aout[(size_t)grow * 1024 + 512 + jglob] = f2bf_hi(hn - bf2f(hi));
    }
  }
}

// ---------------- decoders + gumbel sampling (wave per row) ----------------
template <int K>
__global__ __launch_bounds__(256) void decide_step(
    const float* __restrict__ h, const float* __restrict__ wn,
    const float* __restrict__ bn, const float* __restrict__ wopi,
    const float* __restrict__ bopi, const float* __restrict__ gum,
    float* __restrict__ oan, float* __restrict__ oao,
    float* __restrict__ oln, float* __restrict__ olo,
    float* __restrict__ oen, float* __restrict__ oeo,
    int* __restrict__ act_next, const int* __restrict__ hidx, int hmode,
    const int* __restrict__ cls_prev, int* __restrict__ cls_out) {
  const int lane = threadIdx.x & 63;
  const int r = (blockIdx.x << 2) + (threadIdx.x >> 6);
  const int idx = (hmode == 0) ? 0 : (hmode == 1 ? r : hidx[r]);
  const float* hr = h + (size_t)idx * Hsz;
  const float4 hv0 = *(const float4*)(hr + (lane << 3));
  const float4 hv1 = *(const float4*)(hr + (lane << 3) + 4);

  float nl[K];
#pragma unroll
  for (int j = 0; j < K; ++j) {
    const float* w = wn + (size_t)j * Hsz;
    float4 w0 = *(const float4*)(w + (lane << 3));
    float4 w1 = *(const float4*)(w + (lane << 3) + 4);
    float v = hv0.x * w0.x + hv0.y * w0.y + hv0.z * w0.z + hv0.w * w0.w +
              hv1.x * w1.x + hv1.y * w1.y + hv1.z * w1.z + hv1.w * w1.w;
#pragma unroll
    for (int off = 32; off > 0; off >>= 1) v += __shfl_xor(v, off, 64);
    nl[j] = 2.5f * tanhf((v + bn[j]) / 5.0f);
  }
  float ol[8];
#pragma unroll
  for (int j = 0; j < 8; ++j) {
    const float* w = wopi + (size_t)j * Hsz;
    float4 w0 = *(const float4*)(w + (lane << 3));
    float4 w1 = *(const float4*)(w + (lane << 3) + 4);
    float v = hv0.x * w0.x + hv0.y * w0.y + hv0.z * w0.z + hv0.w * w0.w +
              hv1.x * w1.x + hv1.y * w1.y + hv1.z * w1.z + hv1.w * w1.w;
#pragma unroll
    for (int off = 32; off > 0; off >>= 1) v += __shfl_xor(v, off, 64);
    ol[j] = (v + bopi[j]) / 5.0f;
  }

  {
    const float* g = gum + (size_t)r * 8;
    float m = nl[0];
#pragma unroll
    for (int j = 1; j < K; ++j) m = fmaxf(m, nl[j]);
    float se = 0.0f;
#pragma unroll
    for (int j = 0; j < K; ++j) se += expf(nl[j] - m);
    float lse = logf(se);
    int a = 0;
    float best = nl[0] + g[0];
#pragma unroll
    for (int j = 1; j < K; ++j) {
      float v = nl[j] + g[j];
      if (v > best) { best = v; a = j; }
    }
    float ent = 0.0f, sel = 0.0f;
#pragma unroll
    for (int j = 0; j < K; ++j) {
      float lp = nl[j] - m - lse;
      ent -= lp * expf(lp);
      if (j == a) sel = lp;
    }
    if (lane == 0) { oan[r] = (float)a; oln[r] = sel; oen[r] = ent; }
  }
  {
    const float* g = gum + (size_t)Bsz * 8 + (size_t)r * 8;
    float m = ol[0];
#pragma unroll
    for (int j = 1; j < 8; ++j) m = fmaxf(m, ol[j]);
    float se = 0.0f;
#pragma unroll
    for (int j = 0; j < 8; ++j) se += expf(ol[j] - m);
    float lse = logf(se);
    int a = 0;
    float best = ol[0] + g[0];
#pragma unroll
    for (int j = 1; j < 8; ++j) {
      float v = ol[j] + g[j];
      if (v > best) { best = v; a = j; }
    }
    float ent = 0.0f, sel = 0.0f;
#pragma unroll
    for (int j = 0; j < 8; ++j) {
      float lp = ol[j] - m - lse;
      ent -= lp * expf(lp);
      if (j == a) sel = lp;
    }
    if (lane == 0) {
      oao[r] = (float)a; olo[r] = sel; oeo[r] = ent;
      act_next[r] = a;
      if (cls_out) cls_out[r] = (cls_prev ? cls_prev[r] * 8 : 0) + a;
    }
  }
}

// ---------------------------------------------------------------------------
extern "C" void kernel_launch(void* const* d_in, const int* in_sizes, int n_in,
                              void* d_out, int out_size, void* d_ws,
                              size_t ws_size, hipStream_t stream) {
  (void)in_sizes; (void)n_in; (void)out_size; (void)ws_size;
  const float* emb = (const float*)d_in[0];
  const float* w_ih = (const float*)d_in[1];
  const float* w_hh = (const float*)d_in[2];
  const float* b_ih = (const float*)d_in[3];
  const float* b_hh = (const float*)d_in[4];
  const float* wn[4] = {(const float*)d_in[5], (const float*)d_in[7],
                        (const float*)d_in[9], (const float*)d_in[11]};
  const float* bn[4] = {(const float*)d_in[6], (const float*)d_in[8],
                        (const float*)d_in[10], (const float*)d_in[12]};
  const float* wop = (const float*)d_in[13];
  const float* bop = (const float*)d_in[14];
  const float* gum = (const float*)d_in[15];

  float* ws = (float*)d_ws;
  float* E = ws;                 ws += 9 * G4H;
  float* Eperm = ws;             ws += 9 * G4H;
  float* h1 = ws;                ws += Hsz;
  float* c1 = ws;                ws += Hsz;
  float* h2 = ws;                ws += 8 * Hsz;
  float* c2 = ws;                ws += 8 * Hsz;
  float* h3 = ws;                ws += 64 * Hsz;
  float* c3 = ws;                ws += 64 * Hsz;
  float* h4 = ws;                ws += 512 * Hsz;
  float* c4 = ws;                ws += 512 * Hsz;
  float* Gearly = ws;            // 4 MB used by early path...
  ushort_t* AcatB = (ushort_t*)Gearly;  // ...region reused (8 MB) from step 5
  ws += (8u << 20) / 4;
  ushort_t* AcatA = (ushort_t*)ws;      ws += (8u << 20) / 4;
  ushort_t* Wcat = (ushort_t*)ws;       ws += (6u << 20) / 4;
  float* hA = ws;                ws += (size_t)Bsz * Hsz;
  float* cF = ws;                ws += (size_t)Bsz * Hsz;
  int* act = (int*)ws;
  int* cls = act + Bsz;

  float* out = (float*)d_out;
  const size_t SZ = (size_t)16 * Bsz;

  auto decide = [&](int s, const float* h, int hmode, const int* hidx,
                    const int* cls_prev, int* cls_out) {
    const int i = s >> 1;
    float* oan = out + (size_t)(2 * s) * Bsz;
    float* oao = out + (size_t)(2 * s + 1) * Bsz;
    float* oln = out + SZ + (size_t)(2 * s) * Bsz;
    float* olo = out + SZ + (size_t)(2 * s + 1) * Bsz;
    float* oen = out + 2 * SZ + (size_t)(2 * s) * Bsz;
    float* oeo = out + 2 * SZ + (size_t)(2 * s + 1) * Bsz;
    const float* gn = gum + (size_t)(2 * s) * Bsz * 8;
    const float* wopi = wop + (size_t)i * 8 * Hsz;
    const float* bopi = bop + (size_t)i * 8;
    switch (i) {
      case 0:
        decide_step<2><<<Bsz / 4, 256, 0, stream>>>(h, wn[0], bn[0], wopi, bopi,
            gn, oan, oao, oln, olo, oen, oeo, act, hidx, hmode, cls_prev, cls_out);
        break;
      case 1:
        decide_step<3><<<Bsz / 4, 256, 0, stream>>>(h, wn[1], bn[1], wopi, bopi,
            gn, oan, oao, oln, olo, oen, oeo, act, hidx, hmode, cls_prev, cls_out);
        break;
      case 2:
        decide_step<4><<<Bsz / 4, 256, 0, stream>>>(h, wn[2], bn[2], wopi, bopi,
            gn, oan, oao, oln, olo, oen, oeo, act, hidx, hmode, cls_prev, cls_out);
        break;
      default:
        decide_step<5><<<Bsz / 4, 256, 0, stream>>>(h, wn[3], bn[3], wopi, bopi,
            gn, oan, oao, oln, olo, oen, oeo, act, hidx, hmode, cls_prev, cls_out);
        break;
    }
  };

  precompute_E<<<(9 * G4H) / 256, 256, 0, stream>>>(emb, w_ih, b_ih, b_hh, E,
                                                    Eperm);
  build_wcat<<<dim3(6, 2048), 256, 0, stream>>>(w_hh, Wcat);

  // step 0: gates = E[0] uniform -> 1-class h1,c1
  step_pw<<<2, 256, 0, stream>>>(nullptr, E, nullptr, h1, c1, 1);
  decide(0, h1, 0, nullptr, nullptr, cls);

  // step 1: 1-class GEMM -> 8-class h2,c2
  class_gemm<<<512, 256, 0, stream>>>(h1, w_hh, Gearly, 1);
  step_pw<<<16, 256, 0, stream>>>(Gearly, E, c1, h2, c2, 8);
  decide(1, h2, 2, cls, cls, cls);

  // step 2: 8-class GEMM -> 64-class h3,c3
  class_gemm<<<4096, 256, 0, stream>>>(h2, w_hh, Gearly, 8);
  step_pw<<<128, 256, 0, stream>>>(Gearly, E, c2, h3, c3, 64);
  decide(2, h3, 2, cls, cls, cls);

  // step 3: 64-class GEMM -> 512-class h4,c4
  class_gemm<<<32768, 256, 0, stream>>>(h3, w_hh, Gearly, 64);
  step_pw<<<1024, 256, 0, stream>>>(Gearly, E, c3, h4, c4, 512);
  decide(3, h4, 2, cls, nullptr, nullptr);

  // step 4: 512-class GEMM, expand to full rows (+ emit AcatA for step 5)
  gemm64<<<256, 256, 0, stream>>>(h4, w_hh, Gearly);
  expand_pw<<<(Bsz * Hsz) / 256, 256, 0, stream>>>(Gearly, E, c4, cls, act, hA,
                                                   cF, AcatA);
  decide(4, hA, 1, nullptr, nullptr, nullptr);

  // steps 5-7: split-bf16 MFMA GEMM + fused pointwise (A-cat ping-pong)
  ushort_t* ain = AcatA;
  ushort_t* aout = AcatB;
  for (int s = 5; s < 8; ++s) {
    gemm_bf16_lstm<<<512, 256, 0, stream>>>(ain, Wcat, Eperm, act, cF, hA, aout);
    decide(s, hA, 1, nullptr, nullptr, nullptr);
    ushort_t* t = ain; ain = aout; aout = t;
  }
}

// Round 4
// 482.679 us; speedup vs baseline: 1.7976x; 1.7976x over previous
//
#include <hip/hip_runtime.h>

// ---------------------------------------------------------------------------
// NASNet controller: 8 sequential LSTM steps (B=4096, H=512) + 16 decisions.
//  - Steps 1-4 run on class representatives (1/8/64/512 rows): rows only
//    differ through sampled op tokens (8^s classes).
//  - Steps 5-7: full GEMMs on the MFMA pipe via split-bf16 (hi+lo) emulation:
//    A*B ~= Ahi*Bhi + Ahi*Blo + Alo*Bhi  == one bf16 GEMM with K=1536.
//  - R4: XOR-swizzled LDS layout (16B-chunk c of row r stored at c^(r&7)) to
//    kill the 16-way bank conflicts of the stride-128B tile. Swizzle is
//    implemented via per-lane SOURCE address remap in global_load_lds staging
//    (dest must stay lane-contiguous) + matching XOR in fragment reads.
// ---------------------------------------------------------------------------

constexpr int Bsz = 4096;
constexpr int Hsz = 512;
constexpr int G4H = 2048;

typedef unsigned short ushort_t;
using short8 = __attribute__((ext_vector_type(8))) short;
using f32x4 = __attribute__((ext_vector_type(4))) float;

__device__ __forceinline__ ushort_t f2bf_hi(float f) {
  unsigned u = __float_as_uint(f);
  u += 0x7FFF + ((u >> 16) & 1);  // RNE
  return (ushort_t)(u >> 16);
}
__device__ __forceinline__ float bf2f(ushort_t h) {
  return __uint_as_float((unsigned)h << 16);
}

__device__ __forceinline__ void glds16(const void* gsrc, void* ldst) {
  __builtin_amdgcn_global_load_lds(
      (const __attribute__((address_space(1))) void*)gsrc,
      (__attribute__((address_space(3))) void*)ldst, 16, 0, 0);
}

// ---------------- E = emb @ w_ih^T + b_ih + b_hh (std + ct-permuted) -------
__global__ __launch_bounds__(256) void precompute_E(
    const float* __restrict__ emb, const float* __restrict__ w_ih,
    const float* __restrict__ b_ih, const float* __restrict__ b_hh,
    float* __restrict__ E, float* __restrict__ Eperm) {
  int idx = blockIdx.x * 256 + threadIdx.x;  // t*2048 + col
  int t = idx >> 11;
  int col = idx & 2047;
  const float* er = emb + (size_t)t * Hsz;
  const float* wr = w_ih + (size_t)col * Hsz;
  float acc = 0.0f;
  for (int k = 0; k < Hsz; k += 4) {
    float4 e = *(const float4*)(er + k);
    float4 w = *(const float4*)(wr + k);
    acc += e.x * w.x + e.y * w.y + e.z * w.z + e.w * w.w;
  }
  float v = acc + b_ih[col] + b_hh[col];
  E[idx] = v;
  int g = col >> 9, j = col & 511;
  Eperm[(size_t)t * G4H + (j << 2) + g] = v;
}

// ---------------- W_cat: [2048 ct rows][1536] bf16 = [hi | lo | hi] --------
__global__ __launch_bounds__(256) void build_wcat(
    const float* __restrict__ w_hh, ushort_t* __restrict__ Wcat) {
  int ct = blockIdx.y;
  int k = blockIdx.x * 256 + threadIdx.x;  // 0..1535
  int j = ct >> 2, g = ct & 3;
  const float* srcrow = w_hh + (size_t)(g * 512 + j) * Hsz;
  ushort_t out;
  if (k < 512) {
    out = f2bf_hi(srcrow[k]);
  } else if (k < 1024) {
    float x = srcrow[k - 512];
    ushort_t hi = f2bf_hi(x);
    out = f2bf_hi(x - bf2f(hi));
  } else {
    out = f2bf_hi(srcrow[k - 1024]);
  }
  Wcat[(size_t)ct * 1536 + k] = out;
}

// ---------------- class GEMM: G[q][col] = dot(h[q], w[col]) ----------------
__global__ __launch_bounds__(256) void class_gemm(
    const float* __restrict__ h, const float* __restrict__ w,
    float* __restrict__ G, int nq) {
  const int wid = (blockIdx.x << 2) + (threadIdx.x >> 6);
  const int lane = threadIdx.x & 63;
  const int q = wid >> 11;
  const int col = wid & 2047;
  if (q >= nq) return;
  const float* hr = h + (size_t)q * Hsz + (lane << 3);
  const float* wr = w + (size_t)col * Hsz + (lane << 3);
  float4 a0 = *(const float4*)(hr);
  float4 a1 = *(const float4*)(hr + 4);
  float4 b0 = *(const float4*)(wr);
  float4 b1 = *(const float4*)(wr + 4);
  float v = a0.x * b0.x + a0.y * b0.y + a0.z * b0.z + a0.w * b0.w +
            a1.x * b1.x + a1.y * b1.y + a1.z * b1.z + a1.w * b1.w;
#pragma unroll
  for (int off = 32; off > 0; off >>= 1) v += __shfl_xor(v, off, 64);
  if (lane == 0) G[(size_t)q * G4H + col] = v;
}

// ---------------- 64x64-tiled fp32 GEMM (step 4, M=512) --------------------
__global__ __launch_bounds__(256) void gemm64(
    const float* __restrict__ A, const float* __restrict__ Bw,
    float* __restrict__ G) {
  constexpr int LDA = 68;
  __shared__ float As[16 * LDA];
  __shared__ float Bs[16 * LDA];
  const int tid = threadIdx.x;
  const int bx = blockIdx.x & 31;
  const int by = blockIdx.x >> 5;
  const int r0 = by * 64, c0 = bx * 64;
  const int tx = tid & 15, ty = tid >> 4;
  const int lr = tid >> 2;
  const int lk = (tid & 3) << 2;
  const float* Ar = A + (size_t)(r0 + lr) * Hsz;
  const float* Br = Bw + (size_t)(c0 + lr) * Hsz;
  float acc[4][4];
#pragma unroll
  for (int i = 0; i < 4; ++i)
#pragma unroll
    for (int j = 0; j < 4; ++j) acc[i][j] = 0.0f;

  for (int k0 = 0; k0 < Hsz; k0 += 16) {
    float4 a = *(const float4*)(Ar + k0 + lk);
    float4 b = *(const float4*)(Br + k0 + lk);
    __syncthreads();
    As[(lk + 0) * LDA + lr] = a.x;
    As[(lk + 1) * LDA + lr] = a.y;
    As[(lk + 2) * LDA + lr] = a.z;
    As[(lk + 3) * LDA + lr] = a.w;
    Bs[(lk + 0) * LDA + lr] = b.x;
    Bs[(lk + 1) * LDA + lr] = b.y;
    Bs[(lk + 2) * LDA + lr] = b.z;
    Bs[(lk + 3) * LDA + lr] = b.w;
    __syncthreads();
#pragma unroll
    for (int kk = 0; kk < 16; ++kk) {
      float4 av = *(const float4*)&As[kk * LDA + (ty << 2)];
      float4 bv = *(const float4*)&Bs[kk * LDA + (tx << 2)];
      float avs[4] = {av.x, av.y, av.z, av.w};
      float bvs[4] = {bv.x, bv.y, bv.z, bv.w};
#pragma unroll
      for (int i = 0; i < 4; ++i)
#pragma unroll
        for (int j = 0; j < 4; ++j) acc[i][j] = fmaf(avs[i], bvs[j], acc[i][j]);
    }
  }
#pragma unroll
  for (int i = 0; i < 4; ++i)
#pragma unroll
    for (int j = 0; j < 4; ++j)
      G[(size_t)(r0 + (ty << 2) + i) * G4H + c0 + (tx << 2) + j] = acc[i][j];
}

// ---------------- class pointwise ------------------------------------------
__global__ __launch_bounds__(256) void step_pw(
    const float* __restrict__ G, const float* __restrict__ E,
    const float* __restrict__ c_prev, float* __restrict__ h_out,
    float* __restrict__ c_out, int nq) {
  int idx = blockIdx.x * 256 + threadIdx.x;
  if (idx >= nq * Hsz) return;
  int q = idx >> 9, j = idx & 511;
  int gq = q >> 3, er = q & 7;
  const float* Eg = E + (size_t)er * G4H;
  float iv = Eg[j], fv = Eg[512 + j], gv = Eg[1024 + j], ov = Eg[1536 + j];
  if (G) {
    const float* Gg = G + (size_t)gq * G4H;
    iv += Gg[j]; fv += Gg[512 + j]; gv += Gg[1024 + j]; ov += Gg[1536 + j];
  }
  float cp = c_prev ? c_prev[(size_t)gq * Hsz + j] : 0.0f;
  float ig = 1.0f / (1.0f + expf(-iv));
  float fg = 1.0f / (1.0f + expf(-fv));
  float gg = tanhf(gv);
  float og = 1.0f / (1.0f + expf(-ov));
  float cn = fg * cp + ig * gg;
  c_out[idx] = cn;
  h_out[idx] = og * tanhf(cn);
}

// ---------------- step-4 expansion: classes (512) -> rows (4096) -----------
__global__ __launch_bounds__(256) void expand_pw(
    const float* __restrict__ G, const float* __restrict__ E,
    const float* __restrict__ c4, const int* __restrict__ cls3,
    const int* __restrict__ act3, float* __restrict__ h_out,
    float* __restrict__ c_out, ushort_t* __restrict__ Acat) {
  int idx = blockIdx.x * 256 + threadIdx.x;
  int r = idx >> 9, j = idx & 511;
  int q = cls3[r], er = act3[r];
  const float* Eg = E + (size_t)er * G4H;
  const float* Gg = G + (size_t)q * G4H;
  float iv = Gg[j] + Eg[j];
  float fv = Gg[512 + j] + Eg[512 + j];
  float gv = Gg[1024 + j] + Eg[1024 + j];
  float ov = Gg[1536 + j] + Eg[1536 + j];
  float cp = c4[(size_t)q * Hsz + j];
  float ig = 1.0f / (1.0f + expf(-iv));
  float fg = 1.0f / (1.0f + expf(-fv));
  float gg = tanhf(gv);
  float og = 1.0f / (1.0f + expf(-ov));
  float cn = fg * cp + ig * gg;
  float hn = og * tanhf(cn);
  c_out[idx] = cn;
  h_out[idx] = hn;
  ushort_t hi = f2bf_hi(hn);
  Acat[(size_t)r * 1024 + j] = hi;
  Acat[(size_t)r * 1024 + 512 + j] = f2bf_hi(hn - bf2f(hi));
}

// ---------------- split-bf16 MFMA GEMM + fused LSTM pointwise --------------
// C[4096 x 2048ct] = Acat(logical [hi|hi|lo]) @ Wcat^T (rows = ct, [hi|lo|hi])
// tile 128x128, BK=64, 4 waves x (4x4 16x16x32 tiles). XOR-swizzled LDS.
__global__ __launch_bounds__(256) void gemm_bf16_lstm(
    const ushort_t* __restrict__ Acat, const ushort_t* __restrict__ Wcat,
    const float* __restrict__ Eperm, const int* __restrict__ act,
    float* __restrict__ cF, float* __restrict__ h_out,
    ushort_t* __restrict__ Aout) {
  __shared__ union {
    struct { ushort_t A[128 * 64]; ushort_t B[128 * 64]; } s;  // 32 KB
    float C[64 * 132];                                         // 33.8 KB
  } sm;

  const int tid = threadIdx.x;
  const int wave = tid >> 6, lane = tid & 63;
  const int bx = blockIdx.x & 15;   // 16 col tiles
  const int by = blockIdx.x >> 4;   // 32 row tiles
  const int r0 = by * 128, c0 = bx * 128;
  const int wr = (wave >> 1) * 64, wc = (wave & 1) * 64;
  const int mrow = lane & 15, quad = lane >> 4;

  // staging: lane l writes LDS chunk l of its 1KB region (8 rows x 8 chunks);
  // source chunk is XOR-swizzled so physical chunk pc of row lr holds logical
  // chunk pc^lr.
  const int slr = lane >> 3;                    // row-in-region 0..7
  const int ssw = ((lane & 7) ^ slr) << 3;      // swizzled source chunk offset

  f32x4 acc[4][4];
#pragma unroll
  for (int i = 0; i < 4; ++i)
#pragma unroll
    for (int jt = 0; jt < 4; ++jt) acc[i][jt] = (f32x4){0.f, 0.f, 0.f, 0.f};

  for (int k0 = 0; k0 < 1536; k0 += 64) {
    const int ak = (k0 < 512) ? k0 : k0 - 512;  // A dup-block remap
    __syncthreads();  // prior iter's ds_reads done before overwrite
#pragma unroll
    for (int q = 0; q < 8; ++q) {
      const int g = q * 4 + wave;
      if (g < 16) {
        const int row = r0 + g * 8 + slr;
        glds16(Acat + (size_t)row * 1024 + ak + ssw,
               (char*)sm.s.A + g * 1024);
      } else {
        const int row = c0 + (g - 16) * 8 + slr;
        glds16(Wcat + (size_t)row * 1536 + k0 + ssw,
               (char*)sm.s.B + (g - 16) * 1024);
      }
    }
    __syncthreads();
#pragma unroll
    for (int kk = 0; kk < 2; ++kk) {
      const int swr = ((kk * 4 + quad) ^ (mrow & 7)) << 3;  // swizzled chunk
      short8 a[4], b[4];
#pragma unroll
      for (int i = 0; i < 4; ++i)
        a[i] = *(const short8*)&sm.s.A[(wr + i * 16 + mrow) * 64 + swr];
#pragma unroll
      for (int jt = 0; jt < 4; ++jt)
        b[jt] = *(const short8*)&sm.s.B[(wc + jt * 16 + mrow) * 64 + swr];
#pragma unroll
      for (int i = 0; i < 4; ++i)
#pragma unroll
        for (int jt = 0; jt < 4; ++jt)
          acc[i][jt] = __builtin_amdgcn_mfma_f32_16x16x32_bf16(
              a[i], b[jt], acc[i][jt], 0, 0, 0);
    }
  }

  // ---- epilogue: two 64-row phases through LDS, fused LSTM pointwise ----
  const int jj = tid & 31;         // j-local 0..31
  const int rbase = tid >> 5;      // 0..7
#pragma unroll
  for (int p = 0; p < 2; ++p) {
    __syncthreads();  // phase 0: K-loop reads done; phase 1: prev consume done
    if ((wr >> 6) == p) {
#pragma unroll
      for (int i = 0; i < 4; ++i)
#pragma unroll
        for (int jt = 0; jt < 4; ++jt)
#pragma unroll
          for (int rg = 0; rg < 4; ++rg)
            sm.C[(i * 16 + quad * 4 + rg) * 132 + wc + jt * 16 + mrow] =
                acc[i][jt][rg];
    }
    __syncthreads();
#pragma unroll
    for (int rp = 0; rp < 8; ++rp) {
      const int rl = rbase * 8 + rp;           // 0..63
      const int grow = r0 + p * 64 + rl;
      float4 g4 = *(float4*)&sm.C[rl * 132 + jj * 4];
      const int a = act[grow];
      const int jglob = (c0 >> 2) + jj;        // 0..511
      float4 e4 = *(const float4*)&Eperm[(size_t)a * G4H + c0 + jj * 4];
      float iv = g4.x + e4.x, fv = g4.y + e4.y;
      float gv = g4.z + e4.z, ov = g4.w + e4.w;
      float ig = 1.0f / (1.0f + expf(-iv));
      float fg = 1.0f / (1.0f + expf(-fv));
      float gg = tanhf(gv);
      float og = 1.0f / (1.0f + expf(-ov));
      const size_t ci = (size_t)grow * Hsz + jglob;
      float cn = fg * cF[ci] + ig * gg;
      float hn = og * tanhf(cn);
      cF[ci] = cn;
      h_out[ci] = hn;
      ushort_t hi = f2bf_hi(hn);
      Aout[(size_t)grow * 1024 + jglob] = hi;
      Aout[(size_t)grow * 1024 + 512 + jglob] = f2bf_hi(hn - bf2f(hi));
    }
  }
}

// ---------------- decoders + gumbel sampling (wave per row) ----------------
template <int K>
__global__ __launch_bounds__(256) void decide_step(
    const float* __restrict__ h, const float* __restrict__ wn,
    const float* __restrict__ bn, const float* __restrict__ wopi,
    const float* __restrict__ bopi, const float* __restrict__ gum,
    float* __restrict__ oan, float* __restrict__ oao,
    float* __restrict__ oln, float* __restrict__ olo,
    float* __restrict__ oen, float* __restrict__ oeo,
    int* __restrict__ act_next, const int* __restrict__ hidx, int hmode,
    const int* __restrict__ cls_prev, int* __restrict__ cls_out) {
  const int lane = threadIdx.x & 63;
  const int r = (blockIdx.x << 2) + (threadIdx.x >> 6);
  const int idx = (hmode == 0) ? 0 : (hmode == 1 ? r : hidx[r]);
  const float* hr = h + (size_t)idx * Hsz;
  const float4 hv0 = *(const float4*)(hr + (lane << 3));
  const float4 hv1 = *(const float4*)(hr + (lane << 3) + 4);

  float nl[K];
#pragma unroll
  for (int j = 0; j < K; ++j) {
    const float* w = wn + (size_t)j * Hsz;
    float4 w0 = *(const float4*)(w + (lane << 3));
    float4 w1 = *(const float4*)(w + (lane << 3) + 4);
    float v = hv0.x * w0.x + hv0.y * w0.y + hv0.z * w0.z + hv0.w * w0.w +
              hv1.x * w1.x + hv1.y * w1.y + hv1.z * w1.z + hv1.w * w1.w;
#pragma unroll
    for (int off = 32; off > 0; off >>= 1) v += __shfl_xor(v, off, 64);
    nl[j] = 2.5f * tanhf((v + bn[j]) / 5.0f);
  }
  float ol[8];
#pragma unroll
  for (int j = 0; j < 8; ++j) {
    const float* w = wopi + (size_t)j * Hsz;
    float4 w0 = *(const float4*)(w + (lane << 3));
    float4 w1 = *(const float4*)(w + (lane << 3) + 4);
    float v = hv0.x * w0.x + hv0.y * w0.y + hv0.z * w0.z + hv0.w * w0.w +
              hv1.x * w1.x + hv1.y * w1.y + hv1.z * w1.z + hv1.w * w1.w;
#pragma unroll
    for (int off = 32; off > 0; off >>= 1) v += __shfl_xor(v, off, 64);
    ol[j] = (v + bopi[j]) / 5.0f;
  }

  {
    const float* g = gum + (size_t)r * 8;
    float m = nl[0];
#pragma unroll
    for (int j = 1; j < K; ++j) m = fmaxf(m, nl[j]);
    float se = 0.0f;
#pragma unroll
    for (int j = 0; j < K; ++j) se += expf(nl[j] - m);
    float lse = logf(se);
    int a = 0;
    float best = nl[0] + g[0];
#pragma unroll
    for (int j = 1; j < K; ++j) {
      float v = nl[j] + g[j];
      if (v > best) { best = v; a = j; }
    }
    float ent = 0.0f, sel = 0.0f;
#pragma unroll
    for (int j = 0; j < K; ++j) {
      float lp = nl[j] - m - lse;
      ent -= lp * expf(lp);
      if (j == a) sel = lp;
    }
    if (lane == 0) { oan[r] = (float)a; oln[r] = sel; oen[r] = ent; }
  }
  {
    const float* g = gum + (size_t)Bsz * 8 + (size_t)r * 8;
    float m = ol[0];
#pragma unroll
    for (int j = 1; j < 8; ++j) m = fmaxf(m, ol[j]);
    float se = 0.0f;
#pragma unroll
    for (int j = 0; j < 8; ++j) se += expf(ol[j] - m);
    float lse = logf(se);
    int a = 0;
    float best = ol[0] + g[0];
#pragma unroll
    for (int j = 1; j < 8; ++j) {
      float v = ol[j] + g[j];
      if (v > best) { best = v; a = j; }
    }
    float ent = 0.0f, sel = 0.0f;
#pragma unroll
    for (int j = 0; j < 8; ++j) {
      float lp = ol[j] - m - lse;
      ent -= lp * expf(lp);
      if (j == a) sel = lp;
    }
    if (lane == 0) {
      oao[r] = (float)a; olo[r] = sel; oeo[r] = ent;
      act_next[r] = a;
      if (cls_out) cls_out[r] = (cls_prev ? cls_prev[r] * 8 : 0) + a;
    }
  }
}

// ---------------------------------------------------------------------------
extern "C" void kernel_launch(void* const* d_in, const int* in_sizes, int n_in,
                              void* d_out, int out_size, void* d_ws,
                              size_t ws_size, hipStream_t stream) {
  (void)in_sizes; (void)n_in; (void)out_size; (void)ws_size;
  const float* emb = (const float*)d_in[0];
  const float* w_ih = (const float*)d_in[1];
  const float* w_hh = (const float*)d_in[2];
  const float* b_ih = (const float*)d_in[3];
  const float* b_hh = (const float*)d_in[4];
  const float* wn[4] = {(const float*)d_in[5], (const float*)d_in[7],
                        (const float*)d_in[9], (const float*)d_in[11]};
  const float* bn[4] = {(const float*)d_in[6], (const float*)d_in[8],
                        (const float*)d_in[10], (const float*)d_in[12]};
  const float* wop = (const float*)d_in[13];
  const float* bop = (const float*)d_in[14];
  const float* gum = (const float*)d_in[15];

  float* ws = (float*)d_ws;
  float* E = ws;                 ws += 9 * G4H;
  float* Eperm = ws;             ws += 9 * G4H;
  float* h1 = ws;                ws += Hsz;
  float* c1 = ws;                ws += Hsz;
  float* h2 = ws;                ws += 8 * Hsz;
  float* c2 = ws;                ws += 8 * Hsz;
  float* h3 = ws;                ws += 64 * Hsz;
  float* c3 = ws;                ws += 64 * Hsz;
  float* h4 = ws;                ws += 512 * Hsz;
  float* c4 = ws;                ws += 512 * Hsz;
  float* Gearly = ws;            // 4 MB used by early path...
  ushort_t* AcatB = (ushort_t*)Gearly;  // ...region reused (8 MB) from step 5
  ws += (8u << 20) / 4;
  ushort_t* AcatA = (ushort_t*)ws;      ws += (8u << 20) / 4;
  ushort_t* Wcat = (ushort_t*)ws;       ws += (6u << 20) / 4;
  float* hA = ws;                ws += (size_t)Bsz * Hsz;
  float* cF = ws;                ws += (size_t)Bsz * Hsz;
  int* act = (int*)ws;
  int* cls = act + Bsz;

  float* out = (float*)d_out;
  const size_t SZ = (size_t)16 * Bsz;

  auto decide = [&](int s, const float* h, int hmode, const int* hidx,
                    const int* cls_prev, int* cls_out) {
    const int i = s >> 1;
    float* oan = out + (size_t)(2 * s) * Bsz;
    float* oao = out + (size_t)(2 * s + 1) * Bsz;
    float* oln = out + SZ + (size_t)(2 * s) * Bsz;
    float* olo = out + SZ + (size_t)(2 * s + 1) * Bsz;
    float* oen = out + 2 * SZ + (size_t)(2 * s) * Bsz;
    float* oeo = out + 2 * SZ + (size_t)(2 * s + 1) * Bsz;
    const float* gn = gum + (size_t)(2 * s) * Bsz * 8;
    const float* wopi = wop + (size_t)i * 8 * Hsz;
    const float* bopi = bop + (size_t)i * 8;
    switch (i) {
      case 0:
        decide_step<2><<<Bsz / 4, 256, 0, stream>>>(h, wn[0], bn[0], wopi, bopi,
            gn, oan, oao, oln, olo, oen, oeo, act, hidx, hmode, cls_prev, cls_out);
        break;
      case 1:
        decide_step<3><<<Bsz / 4, 256, 0, stream>>>(h, wn[1], bn[1], wopi, bopi,
            gn, oan, oao, oln, olo, oen, oeo, act, hidx, hmode, cls_prev, cls_out);
        break;
      case 2:
        decide_step<4><<<Bsz / 4, 256, 0, stream>>>(h, wn[2], bn[2], wopi, bopi,
            gn, oan, oao, oln, olo, oen, oeo, act, hidx, hmode, cls_prev, cls_out);
        break;
      default:
        decide_step<5><<<Bsz / 4, 256, 0, stream>>>(h, wn[3], bn[3], wopi, bopi,
            gn, oan, oao, oln, olo, oen, oeo, act, hidx, hmode, cls_prev, cls_out);
        break;
    }
  };

  precompute_E<<<(9 * G4H) / 256, 256, 0, stream>>>(emb, w_ih, b_ih, b_hh, E,
                                                    Eperm);
  build_wcat<<<dim3(6, 2048), 256, 0, stream>>>(w_hh, Wcat);

  // step 0: gates = E[0] uniform -> 1-class h1,c1
  step_pw<<<2, 256, 0, stream>>>(nullptr, E, nullptr, h1, c1, 1);
  decide(0, h1, 0, nullptr, nullptr, cls);

  // step 1: 1-class GEMM -> 8-class h2,c2
  class_gemm<<<512, 256, 0, stream>>>(h1, w_hh, Gearly, 1);
  step_pw<<<16, 256, 0, stream>>>(Gearly, E, c1, h2, c2, 8);
  decide(1, h2, 2, cls, cls, cls);

  // step 2: 8-class GEMM -> 64-class h3,c3
  class_gemm<<<4096, 256, 0, stream>>>(h2, w_hh, Gearly, 8);
  step_pw<<<128, 256, 0, stream>>>(Gearly, E, c2, h3, c3, 64);
  decide(2, h3, 2, cls, cls, cls);

  // step 3: 64-class GEMM -> 512-class h4,c4
  class_gemm<<<32768, 256, 0, stream>>>(h3, w_hh, Gearly, 64);
  step_pw<<<1024, 256, 0, stream>>>(Gearly, E, c3, h4, c4, 512);
  decide(3, h4, 2, cls, nullptr, nullptr);

  // step 4: 512-class GEMM, expand to full rows (+ emit AcatA for step 5)
  gemm64<<<256, 256, 0, stream>>>(h4, w_hh, Gearly);
  expand_pw<<<(Bsz * Hsz) / 256, 256, 0, stream>>>(Gearly, E, c4, cls, act, hA,
                                                   cF, AcatA);
  decide(4, hA, 1, nullptr, nullptr, nullptr);

  // steps 5-7: split-bf16 MFMA GEMM + fused pointwise (A-cat ping-pong)
  ushort_t* ain = AcatA;
  ushort_t* aout = AcatB;
  for (int s = 5; s < 8; ++s) {
    gemm_bf16_lstm<<<512, 256, 0, stream>>>(ain, Wcat, Eperm, act, cF, hA, aout);
    decide(s, hA, 1, nullptr, nullptr, nullptr);
    ushort_t* t = ain; ain = aout; aout = t;
  }
}